// Round 9
// baseline (92.355 us; speedup 1.0000x reference)
//
#include <hip/hip_runtime.h>
#include <hip/hip_bf16.h>
#include <stdint.h>

#define N_ATOMS 131072
#define D_IN    128
#define D_HID   256
#define N_ELEM  4
#define NPAD    (N_ATOMS + N_ELEM * 64)   // 131328 slots max
#define K4_BLOCKS 512                      // 2/CU, expert = blockIdx&3
#define HIST_BLOCKS 128                    // 128 x 1024 atoms

typedef __attribute__((ext_vector_type(8))) short bf16x8;
typedef __attribute__((ext_vector_type(4))) float f32x4;

// ws layout (bytes):
//   [0,       262144): W1t bf16 [4][256][128] (h-major, k contiguous)
//   [262272,  270464): bpart4[512*4] float (per-wave partials)
//   [270592,  272640): blockCounts[128][4] int
//   [287232,  812544): sortedIdx[NPAD] int
#define WS_BPART  262272
#define WS_BCNT   270592
#define WS_SIDX   287232

__device__ __forceinline__ unsigned short f2bf_rne(float f) {
    union { float f; unsigned u; } v; v.f = f;
    unsigned r = v.u + 0x7FFFu + ((v.u >> 16) & 1u);   // RNE
    return (unsigned short)(r >> 16);
}

__device__ __forceinline__ bf16x8 cvt8(f32x4 v0, f32x4 v1) {
    uint4 o;
    o.x = (__float_as_uint(v0[0]) >> 16) | (__float_as_uint(v0[1]) & 0xFFFF0000u);
    o.y = (__float_as_uint(v0[2]) >> 16) | (__float_as_uint(v0[3]) & 0xFFFF0000u);
    o.z = (__float_as_uint(v1[0]) >> 16) | (__float_as_uint(v1[1]) & 0xFFFF0000u);
    o.w = (__float_as_uint(v1[2]) >> 16) | (__float_as_uint(v1[3]) & 0xFFFF0000u);
    return __builtin_bit_cast(bf16x8, o);
}

// int4 butterfly reduce across a 64-lane wave (all lanes get the total)
__device__ __forceinline__ int4 wave_reduce4(int4 v) {
    #pragma unroll
    for (int off = 32; off; off >>= 1) {
        v.x += __shfl_xor(v.x, off);
        v.y += __shfl_xor(v.y, off);
        v.z += __shfl_xor(v.z, off);
        v.w += __shfl_xor(v.w, off);
    }
    return v;
}

// K1 (fused): blocks 0..31 transpose W1 -> W1t bf16; blocks 32..159 histogram.
__global__ void tnn_k1_fused(const int* __restrict__ eid, int* __restrict__ bcnt,
                             const float* __restrict__ W1, unsigned short* __restrict__ W1t) {
    __shared__ float tile[64][65];
    __shared__ int lc[N_ELEM];
    int t = threadIdx.x;
    if (blockIdx.x < 32) {
        int b  = blockIdx.x;
        int e  = b >> 3;
        int k0 = ((b >> 2) & 1) * 64;
        int h0 = (b & 3) * 64;
        int cg = t & 15;
        int rr = t >> 4;
        const float* src = W1 + ((size_t)e * D_IN + k0) * D_HID + h0;
        #pragma unroll
        for (int j = 0; j < 4; ++j) {
            int row = rr + j * 16;
            f32x4 v = *(const f32x4*)(src + (size_t)row * D_HID + cg * 4);
            tile[row][cg * 4 + 0] = v[0];
            tile[row][cg * 4 + 1] = v[1];
            tile[row][cg * 4 + 2] = v[2];
            tile[row][cg * 4 + 3] = v[3];
        }
        __syncthreads();
        unsigned short* dst = W1t + ((size_t)e * D_HID + h0) * D_IN + k0;
        #pragma unroll
        for (int j = 0; j < 4; ++j) {
            int hrow = rr + j * 16;
            ushort4 o;
            o.x = f2bf_rne(tile[cg * 4 + 0][hrow]);
            o.y = f2bf_rne(tile[cg * 4 + 1][hrow]);
            o.z = f2bf_rne(tile[cg * 4 + 2][hrow]);
            o.w = f2bf_rne(tile[cg * 4 + 3][hrow]);
            *(ushort4*)(dst + (size_t)hrow * D_IN + cg * 4) = o;
        }
    } else {
        int hb = blockIdx.x - 32;
        if (t < N_ELEM) lc[t] = 0;
        __syncthreads();
        int base = hb * 1024;
        #pragma unroll
        for (int r = 0; r < 4; ++r)
            atomicAdd(&lc[eid[base + r * 256 + t]], 1);
        __syncthreads();
        if (t < N_ELEM) bcnt[hb * 4 + t] = lc[t];
    }
}

// K3: scatter; per-block bases computed inline by wave 0 (masked butterfly scan).
__global__ void tnn_k3_scatter(const int* __restrict__ eid, const int* __restrict__ bcnt,
                               int* __restrict__ sortedIdx) {
    __shared__ int lc[N_ELEM];
    __shared__ int base4[N_ELEM];
    int t = threadIdx.x;
    int b = blockIdx.x;
    if (t < N_ELEM) lc[t] = 0;
    if (t < 64) {
        int4 cl = ((const int4*)bcnt)[t];
        int4 ch = ((const int4*)bcnt)[t + 64];
        int4 tot = {cl.x + ch.x, cl.y + ch.y, cl.z + ch.z, cl.w + ch.w};
        tot = wave_reduce4(tot);
        int4 pre = {(t < b) ? cl.x : 0, (t < b) ? cl.y : 0,
                    (t < b) ? cl.z : 0, (t < b) ? cl.w : 0};
        if (t + 64 < b) { pre.x += ch.x; pre.y += ch.y; pre.z += ch.z; pre.w += ch.w; }
        pre = wave_reduce4(pre);
        if (t == 0) {
            int st0 = 0;
            int st1 = st0 + ((tot.x + 63) & ~63);
            int st2 = st1 + ((tot.y + 63) & ~63);
            int st3 = st2 + ((tot.z + 63) & ~63);
            base4[0] = st0 + pre.x;
            base4[1] = st1 + pre.y;
            base4[2] = st2 + pre.z;
            base4[3] = st3 + pre.w;
        }
    }
    __syncthreads();
    int base = b * 1024;
    #pragma unroll
    for (int r = 0; r < 4; ++r) {
        int i = base + r * 256 + t;
        int e = eid[i];
        int rank = atomicAdd(&lc[e], 1);
        sortedIdx[base4[e] + rank] = i;
    }
}

// K4: block stages its expert's FULL W1t into LDS (64 KB, k-major -> conflict
// free) + a 2 KB {b1*C2, w2} table. Wave = 32-atom tile x 256 hidden; A in
// regs (32 VGPR), B via ds_read ping-pong. Register demand ~105 -> no spill.
__global__ __launch_bounds__(256, 2) void tnn_k4_mlp(
        const float* __restrict__ X, const int* __restrict__ sortedIdx,
        const int* __restrict__ bcnt, const unsigned short* __restrict__ W1t,
        const float* __restrict__ b1, const float* __restrict__ W2,
        float* __restrict__ bpart4) {
    __shared__ unsigned char ldsB[65536];   // [16 kblk][256 h][16 B]  (k-major)
    __shared__ float2 ldsBW[256];           // {b1*C2, w2} per h
    const float C2 = 2.8853900817779268f;   // 2*log2(e)

    int t = threadIdx.x;
    int wid  = t >> 6;
    int lane = t & 63;
    int l15  = lane & 15;
    int lk   = lane >> 4;
    int e    = blockIdx.x & 3;
    int q    = blockIdx.x >> 2;              // 0..127

    // ---- per-wave redundant scan of bcnt -> counts + startArr for expert e ----
    int4 cl = ((const int4*)bcnt)[lane];
    int4 ch = ((const int4*)bcnt)[lane + 64];
    int4 tot = {cl.x + ch.x, cl.y + ch.y, cl.z + ch.z, cl.w + ch.w};
    tot = wave_reduce4(tot);
    int cnts[4] = {tot.x, tot.y, tot.z, tot.w};
    int st[5];
    st[0] = 0;
    #pragma unroll
    for (int i = 0; i < 4; ++i) st[i + 1] = st[i] + ((cnts[i] + 63) & ~63);
    int bstart = st[e];
    int cnt    = cnts[e];
    int rend   = bstart + cnt;
    int Te     = (st[e + 1] - bstart) >> 5;       // 32-atom tiles
    int fb     = (cnt > 0) ? sortedIdx[bstart] : 0;

    // ---- stage B (k-major): thread t = h-row t; write block j at j*4096+t*16 ----
    {
        const unsigned short* src = W1t + ((size_t)e * D_HID + t) * D_IN;
        #pragma unroll
        for (int j = 0; j < 16; ++j) {
            bf16x8 v = *(const bf16x8*)(src + j * 8);
            *(bf16x8*)(ldsB + j * 4096 + t * 16) = v;
        }
        ldsBW[t] = make_float2(b1[e * D_HID + t] * C2, W2[e * D_HID + t]);
    }
    __syncthreads();

    unsigned ldso = (unsigned)lk * 4096u + (unsigned)l15 * 16u;

    float partial = 0.f;
    for (int tt = q * 4 + wid; tt < Te; tt += 512) {
        int tb = bstart + tt * 32;
        bool full = (tb + 32 <= rend);

        int slot0 = tb + l15, slot1 = tb + 16 + l15;
        int r0 = (slot0 < rend) ? sortedIdx[slot0] : fb;
        int r1 = (slot1 < rend) ? sortedIdx[slot1] : fb;

        // ---- A: 32 atoms x 128 k -> regs (load+convert inline, low pressure) ----
        bf16x8 a0[4], a1[4];
        {
            const float* x0 = X + (size_t)r0 * D_IN + lk * 8;
            #pragma unroll
            for (int ks = 0; ks < 4; ++ks)
                a0[ks] = cvt8(*(const f32x4*)(x0 + ks * 32), *(const f32x4*)(x0 + ks * 32 + 4));
            const float* x1 = X + (size_t)r1 * D_IN + lk * 8;
            #pragma unroll
            for (int ks = 0; ks < 4; ++ks)
                a1[ks] = cvt8(*(const f32x4*)(x1 + ks * 32), *(const f32x4*)(x1 + ks * 32 + 4));
        }

        float fnval = 8.f;
        if (!full) {
            int nv = 0;
            #pragma unroll
            for (int m = 0; m < 2; ++m)
                #pragma unroll
                for (int r = 0; r < 4; ++r)
                    nv += (tb + m * 16 + lk * 4 + r < rend) ? 1 : 0;
            fnval = (float)nv;
        }

        // ---- nt loop: ds_read ping-pong + 8 MFMA + epilogue ----
        bf16x8 cur[4], nxt[4];
        #pragma unroll
        for (int ks = 0; ks < 4; ++ks)
            cur[ks] = *(const bf16x8*)(ldsB + ldso + ks * 16384);

        #pragma unroll
        for (int nt = 0; nt < 16; ++nt) {
            float2 bw = ldsBW[nt * 16 + l15];
            if (nt < 15) {
                #pragma unroll
                for (int ks = 0; ks < 4; ++ks)
                    nxt[ks] = *(const bf16x8*)(ldsB + ldso + ks * 16384 + (nt + 1) * 256);
            }

            f32x4 acc0 = {0.f, 0.f, 0.f, 0.f};
            f32x4 acc1 = {0.f, 0.f, 0.f, 0.f};
            #pragma unroll
            for (int ks = 0; ks < 4; ++ks) {
                acc0 = __builtin_amdgcn_mfma_f32_16x16x32_bf16(a0[ks], cur[ks], acc0, 0, 0, 0);
                acc1 = __builtin_amdgcn_mfma_f32_16x16x32_bf16(a1[ks], cur[ks], acc1, 0, 0, 0);
            }

            // tanh(p) = 1 - 2/(exp2(C2*p)+1); sum w2*tanh = w2*(nval - 2*sum(rcp))
            float rsum = 0.f;
            #pragma unroll
            for (int r = 0; r < 4; ++r) {
                float e0 = __builtin_amdgcn_exp2f(fmaf(C2, acc0[r], bw.x));
                float e1 = __builtin_amdgcn_exp2f(fmaf(C2, acc1[r], bw.x));
                float rc0 = __builtin_amdgcn_rcpf(e0 + 1.f);
                float rc1 = __builtin_amdgcn_rcpf(e1 + 1.f);
                if (!full) {
                    rc0 = (tb + lk * 4 + r      < rend) ? rc0 : 0.f;
                    rc1 = (tb + 16 + lk * 4 + r < rend) ? rc1 : 0.f;
                }
                rsum += rc0 + rc1;
            }
            partial = fmaf(bw.y, fmaf(-2.f, rsum, fnval), partial);

            if (nt < 15) {
                #pragma unroll
                for (int ks = 0; ks < 4; ++ks) cur[ks] = nxt[ks];
            }
        }
    }

    #pragma unroll
    for (int off = 32; off; off >>= 1)
        partial += __shfl_down(partial, off);
    if (lane == 0) bpart4[blockIdx.x * 4 + wid] = partial;   // plain store
}

// K5: reduce 2048 per-wave partials + analytic bias (counts recomputed inline).
__global__ void tnn_k5_reduce(const float* __restrict__ bpart4, const int* __restrict__ bcnt,
                              const float* __restrict__ b2, float* __restrict__ out) {
    __shared__ float r[4];
    int t = threadIdx.x;
    float s = 0.f;
    #pragma unroll
    for (int j = 0; j < 8; ++j) s += bpart4[j * 256 + t];
    #pragma unroll
    for (int off = 32; off; off >>= 1)
        s += __shfl_down(s, off);
    if ((t & 63) == 0) r[t >> 6] = s;
    __syncthreads();
    if (t < 64) {
        int4 cl = ((const int4*)bcnt)[t];
        int4 ch = ((const int4*)bcnt)[t + 64];
        int4 tot = {cl.x + ch.x, cl.y + ch.y, cl.z + ch.z, cl.w + ch.w};
        tot = wave_reduce4(tot);
        if (t == 0) {
            float acc = r[0] + r[1] + r[2] + r[3];
            acc += (float)tot.x * b2[0];
            acc += (float)tot.y * b2[1];
            acc += (float)tot.z * b2[2];
            acc += (float)tot.w * b2[3];
            out[0] = acc;
        }
    }
}

extern "C" void kernel_launch(void* const* d_in, const int* in_sizes, int n_in,
                              void* d_out, int out_size, void* d_ws, size_t ws_size,
                              hipStream_t stream) {
    const float* X   = (const float*)d_in[0];
    const int*   eid = (const int*)  d_in[1];
    const float* W1  = (const float*)d_in[2];
    const float* b1  = (const float*)d_in[3];
    const float* W2  = (const float*)d_in[4];
    const float* b2  = (const float*)d_in[5];
    float* out = (float*)d_out;

    char* ws = (char*)d_ws;
    unsigned short* W1t = (unsigned short*)ws;
    float* bpart4    = (float*)(ws + WS_BPART);
    int*   bcnt      = (int*)  (ws + WS_BCNT);
    int*   sortedIdx = (int*)  (ws + WS_SIDX);

    hipLaunchKernelGGL(tnn_k1_fused,   dim3(32 + HIST_BLOCKS), dim3(256), 0, stream, eid, bcnt, W1, W1t);
    hipLaunchKernelGGL(tnn_k3_scatter, dim3(HIST_BLOCKS),      dim3(256), 0, stream, eid, bcnt, sortedIdx);
    hipLaunchKernelGGL(tnn_k4_mlp,     dim3(K4_BLOCKS),        dim3(256), 0, stream,
                       X, sortedIdx, bcnt, W1t, b1, W2, bpart4);
    hipLaunchKernelGGL(tnn_k5_reduce,  dim3(1),                dim3(256), 0, stream, bpart4, bcnt, b2, out);
}

// Round 10
// 42.607 us; speedup vs baseline: 2.1676x; 2.1676x over previous
//
#include <hip/hip_runtime.h>
#include <hip/hip_bf16.h>
#include <stdint.h>

#define N_ATOMS 131072
#define D_IN    128
#define D_HID   256
#define N_ELEM  4
#define NPAD    (N_ATOMS + N_ELEM * 64)   // 131328 slots max
#define K4_BLOCKS 256                      // 512 thr each; 2 blocks/CU (LDS-bound)
#define HIST_BLOCKS 128                    // 128 x 1024 atoms

typedef __attribute__((ext_vector_type(8))) short bf16x8;
typedef __attribute__((ext_vector_type(4))) float f32x4;

// ws layout (bytes):
//   [0,       262144): W1t bf16 [4][256][128] (h-major, k contiguous)
//   [262272,  270464): bpart[2048] float (per-wave partials)
//   [270592,  272640): blockCounts[128][4] int
//   [287232,  812544): sortedIdx[NPAD] int
#define WS_BPART  262272
#define WS_BCNT   270592
#define WS_SIDX   287232

__device__ __forceinline__ unsigned short f2bf_rne(float f) {
    union { float f; unsigned u; } v; v.f = f;
    unsigned r = v.u + 0x7FFFu + ((v.u >> 16) & 1u);   // RNE
    return (unsigned short)(r >> 16);
}

__device__ __forceinline__ bf16x8 cvt8(f32x4 v0, f32x4 v1) {
    uint4 o;
    o.x = (__float_as_uint(v0[0]) >> 16) | (__float_as_uint(v0[1]) & 0xFFFF0000u);
    o.y = (__float_as_uint(v0[2]) >> 16) | (__float_as_uint(v0[3]) & 0xFFFF0000u);
    o.z = (__float_as_uint(v1[0]) >> 16) | (__float_as_uint(v1[1]) & 0xFFFF0000u);
    o.w = (__float_as_uint(v1[2]) >> 16) | (__float_as_uint(v1[3]) & 0xFFFF0000u);
    return __builtin_bit_cast(bf16x8, o);
}

// int4 butterfly reduce across a 64-lane wave (all lanes get the total)
__device__ __forceinline__ int4 wave_reduce4(int4 v) {
    #pragma unroll
    for (int off = 32; off; off >>= 1) {
        v.x += __shfl_xor(v.x, off);
        v.y += __shfl_xor(v.y, off);
        v.z += __shfl_xor(v.z, off);
        v.w += __shfl_xor(v.w, off);
    }
    return v;
}

// K1 (fused): blocks 0..31 transpose W1 -> W1t bf16; blocks 32..159 histogram.
__global__ void tnn_k1_fused(const int* __restrict__ eid, int* __restrict__ bcnt,
                             const float* __restrict__ W1, unsigned short* __restrict__ W1t) {
    __shared__ float tile[64][65];
    __shared__ int lc[N_ELEM];
    int t = threadIdx.x;
    if (blockIdx.x < 32) {
        int b  = blockIdx.x;
        int e  = b >> 3;
        int k0 = ((b >> 2) & 1) * 64;
        int h0 = (b & 3) * 64;
        int cg = t & 15;
        int rr = t >> 4;
        const float* src = W1 + ((size_t)e * D_IN + k0) * D_HID + h0;
        #pragma unroll
        for (int j = 0; j < 4; ++j) {
            int row = rr + j * 16;
            f32x4 v = *(const f32x4*)(src + (size_t)row * D_HID + cg * 4);
            tile[row][cg * 4 + 0] = v[0];
            tile[row][cg * 4 + 1] = v[1];
            tile[row][cg * 4 + 2] = v[2];
            tile[row][cg * 4 + 3] = v[3];
        }
        __syncthreads();
        unsigned short* dst = W1t + ((size_t)e * D_HID + h0) * D_IN + k0;
        #pragma unroll
        for (int j = 0; j < 4; ++j) {
            int hrow = rr + j * 16;
            ushort4 o;
            o.x = f2bf_rne(tile[cg * 4 + 0][hrow]);
            o.y = f2bf_rne(tile[cg * 4 + 1][hrow]);
            o.z = f2bf_rne(tile[cg * 4 + 2][hrow]);
            o.w = f2bf_rne(tile[cg * 4 + 3][hrow]);
            *(ushort4*)(dst + (size_t)hrow * D_IN + cg * 4) = o;
        }
    } else {
        int hb = blockIdx.x - 32;
        if (t < N_ELEM) lc[t] = 0;
        __syncthreads();
        int base = hb * 1024;
        #pragma unroll
        for (int r = 0; r < 4; ++r)
            atomicAdd(&lc[eid[base + r * 256 + t]], 1);
        __syncthreads();
        if (t < N_ELEM) bcnt[hb * 4 + t] = lc[t];
    }
}

// K3: scatter; per-block bases computed inline by wave 0 (masked butterfly scan).
__global__ void tnn_k3_scatter(const int* __restrict__ eid, const int* __restrict__ bcnt,
                               int* __restrict__ sortedIdx) {
    __shared__ int lc[N_ELEM];
    __shared__ int base4[N_ELEM];
    int t = threadIdx.x;
    int b = blockIdx.x;
    if (t < N_ELEM) lc[t] = 0;
    if (t < 64) {
        int4 cl = ((const int4*)bcnt)[t];
        int4 ch = ((const int4*)bcnt)[t + 64];
        int4 tot = {cl.x + ch.x, cl.y + ch.y, cl.z + ch.z, cl.w + ch.w};
        tot = wave_reduce4(tot);
        int4 pre = {(t < b) ? cl.x : 0, (t < b) ? cl.y : 0,
                    (t < b) ? cl.z : 0, (t < b) ? cl.w : 0};
        if (t + 64 < b) { pre.x += ch.x; pre.y += ch.y; pre.z += ch.z; pre.w += ch.w; }
        pre = wave_reduce4(pre);
        if (t == 0) {
            int st0 = 0;
            int st1 = st0 + ((tot.x + 63) & ~63);
            int st2 = st1 + ((tot.y + 63) & ~63);
            int st3 = st2 + ((tot.z + 63) & ~63);
            base4[0] = st0 + pre.x;
            base4[1] = st1 + pre.y;
            base4[2] = st2 + pre.z;
            base4[3] = st3 + pre.w;
        }
    }
    __syncthreads();
    int base = b * 1024;
    #pragma unroll
    for (int r = 0; r < 4; ++r) {
        int i = base + r * 256 + t;
        int e = eid[i];
        int rank = atomicAdd(&lc[e], 1);
        sortedIdx[base4[e] + rank] = i;
    }
}

// K4: 512-thread blocks (8 waves); block stages its expert's FULL W1t into LDS
// (64 KB, k-major, conflict-free) + {b1*C2, w2} table. Wave = 32-atom tile x
// 256 hidden; A in regs (32 VGPR); nt loop kept ROLLED (#pragma unroll 1) so
// the scheduler cannot hoist 64 ds_reads and blow the register budget.
__global__ __launch_bounds__(512, 4) void tnn_k4_mlp(
        const float* __restrict__ X, const int* __restrict__ sortedIdx,
        const int* __restrict__ bcnt, const unsigned short* __restrict__ W1t,
        const float* __restrict__ b1, const float* __restrict__ W2,
        float* __restrict__ bpart) {
    __shared__ unsigned char ldsB[65536];   // [16 kblk][256 h][16 B]  (k-major)
    __shared__ float2 ldsBW[256];           // {b1*C2, w2} per h
    const float C2 = 2.8853900817779268f;   // 2*log2(e)

    int t = threadIdx.x;
    int wid  = t >> 6;                       // 0..7
    int lane = t & 63;
    int l15  = lane & 15;
    int lk   = lane >> 4;
    int e    = blockIdx.x & 3;
    int q    = blockIdx.x >> 2;              // 0..63

    // ---- per-wave redundant scan of bcnt -> counts + startArr for expert e ----
    int4 cl = ((const int4*)bcnt)[lane];
    int4 ch = ((const int4*)bcnt)[lane + 64];
    int4 tot = {cl.x + ch.x, cl.y + ch.y, cl.z + ch.z, cl.w + ch.w};
    tot = wave_reduce4(tot);
    int cnts[4] = {tot.x, tot.y, tot.z, tot.w};
    int st[5];
    st[0] = 0;
    #pragma unroll
    for (int i = 0; i < 4; ++i) st[i + 1] = st[i] + ((cnts[i] + 63) & ~63);
    int bstart = st[e];
    int cnt    = cnts[e];
    int rend   = bstart + cnt;
    int Te     = (st[e + 1] - bstart) >> 5;       // 32-atom tiles
    int fb     = (cnt > 0) ? sortedIdx[bstart] : 0;

    // ---- stage B (k-major): thread t = (h-row t>>1, k-half t&1) ----
    {
        int hrow  = t >> 1;
        int khalf = t & 1;
        const unsigned short* src = W1t + ((size_t)e * D_HID + hrow) * D_IN + khalf * 64;
        #pragma unroll
        for (int jj = 0; jj < 8; ++jj) {
            bf16x8 v = *(const bf16x8*)(src + jj * 8);
            *(bf16x8*)(ldsB + (khalf * 8 + jj) * 4096 + hrow * 16) = v;
        }
        if (t < 256) ldsBW[t] = make_float2(b1[e * D_HID + t] * C2, W2[e * D_HID + t]);
    }
    __syncthreads();

    unsigned ldso = (unsigned)lk * 4096u + (unsigned)l15 * 16u;

    float partial = 0.f;
    for (int tt = q * 8 + wid; tt < Te; tt += 512) {
        int tb = bstart + tt * 32;
        bool full = (tb + 32 <= rend);

        int slot0 = tb + l15, slot1 = slot0 + 16;
        int r0 = (slot0 < rend) ? sortedIdx[slot0] : fb;
        int r1 = (slot1 < rend) ? sortedIdx[slot1] : fb;

        // ---- A: 32 atoms x 128 k -> regs ----
        bf16x8 a0[4], a1[4];
        const float* x0 = X + (size_t)r0 * D_IN + lk * 8;
        const float* x1 = X + (size_t)r1 * D_IN + lk * 8;
        #pragma unroll
        for (int ks = 0; ks < 4; ++ks)
            a0[ks] = cvt8(*(const f32x4*)(x0 + ks * 32), *(const f32x4*)(x0 + ks * 32 + 4));
        #pragma unroll
        for (int ks = 0; ks < 4; ++ks)
            a1[ks] = cvt8(*(const f32x4*)(x1 + ks * 32), *(const f32x4*)(x1 + ks * 32 + 4));

        float fnval = 8.f;
        if (!full) {
            int nv = 0;
            #pragma unroll
            for (int m = 0; m < 2; ++m)
                #pragma unroll
                for (int r = 0; r < 4; ++r)
                    nv += (tb + m * 16 + lk * 4 + r < rend) ? 1 : 0;
            fnval = (float)nv;
        }

        // ---- nt loop, kept rolled: 4 ds_read + 8 MFMA + epilogue per iter ----
        #pragma unroll 1
        for (int nt = 0; nt < 16; ++nt) {
            const unsigned char* lb = ldsB + ldso + (unsigned)nt * 256u;
            bf16x8 cur0 = *(const bf16x8*)(lb);
            bf16x8 cur1 = *(const bf16x8*)(lb + 16384);
            bf16x8 cur2 = *(const bf16x8*)(lb + 32768);
            bf16x8 cur3 = *(const bf16x8*)(lb + 49152);
            float2 bw = ldsBW[nt * 16 + l15];

            f32x4 acc0 = {0.f, 0.f, 0.f, 0.f};
            f32x4 acc1 = {0.f, 0.f, 0.f, 0.f};
            acc0 = __builtin_amdgcn_mfma_f32_16x16x32_bf16(a0[0], cur0, acc0, 0, 0, 0);
            acc1 = __builtin_amdgcn_mfma_f32_16x16x32_bf16(a1[0], cur0, acc1, 0, 0, 0);
            acc0 = __builtin_amdgcn_mfma_f32_16x16x32_bf16(a0[1], cur1, acc0, 0, 0, 0);
            acc1 = __builtin_amdgcn_mfma_f32_16x16x32_bf16(a1[1], cur1, acc1, 0, 0, 0);
            acc0 = __builtin_amdgcn_mfma_f32_16x16x32_bf16(a0[2], cur2, acc0, 0, 0, 0);
            acc1 = __builtin_amdgcn_mfma_f32_16x16x32_bf16(a1[2], cur2, acc1, 0, 0, 0);
            acc0 = __builtin_amdgcn_mfma_f32_16x16x32_bf16(a0[3], cur3, acc0, 0, 0, 0);
            acc1 = __builtin_amdgcn_mfma_f32_16x16x32_bf16(a1[3], cur3, acc1, 0, 0, 0);

            // tanh(p) = 1 - 2/(exp2(C2*p)+1); sum w2*tanh = w2*(nval - 2*sum(rcp))
            float rsum = 0.f;
            #pragma unroll
            for (int r = 0; r < 4; ++r) {
                float e0 = __builtin_amdgcn_exp2f(fmaf(C2, acc0[r], bw.x));
                float e1 = __builtin_amdgcn_exp2f(fmaf(C2, acc1[r], bw.x));
                float rc0 = __builtin_amdgcn_rcpf(e0 + 1.f);
                float rc1 = __builtin_amdgcn_rcpf(e1 + 1.f);
                if (!full) {
                    rc0 = (tb + lk * 4 + r      < rend) ? rc0 : 0.f;
                    rc1 = (tb + 16 + lk * 4 + r < rend) ? rc1 : 0.f;
                }
                rsum += rc0 + rc1;
            }
            partial = fmaf(bw.y, fmaf(-2.f, rsum, fnval), partial);
        }
    }

    #pragma unroll
    for (int off = 32; off; off >>= 1)
        partial += __shfl_down(partial, off);
    if (lane == 0) bpart[blockIdx.x * 8 + wid] = partial;   // plain store
}

// K5: reduce 2048 per-wave partials + analytic bias (counts recomputed inline).
__global__ void tnn_k5_reduce(const float* __restrict__ bpart, const int* __restrict__ bcnt,
                              const float* __restrict__ b2, float* __restrict__ out) {
    __shared__ float r[4];
    int t = threadIdx.x;
    float s = 0.f;
    #pragma unroll
    for (int j = 0; j < 8; ++j) s += bpart[j * 256 + t];
    #pragma unroll
    for (int off = 32; off; off >>= 1)
        s += __shfl_down(s, off);
    if ((t & 63) == 0) r[t >> 6] = s;
    __syncthreads();
    if (t < 64) {
        int4 cl = ((const int4*)bcnt)[t];
        int4 ch = ((const int4*)bcnt)[t + 64];
        int4 tot = {cl.x + ch.x, cl.y + ch.y, cl.z + ch.z, cl.w + ch.w};
        tot = wave_reduce4(tot);
        if (t == 0) {
            float acc = r[0] + r[1] + r[2] + r[3];
            acc += (float)tot.x * b2[0];
            acc += (float)tot.y * b2[1];
            acc += (float)tot.z * b2[2];
            acc += (float)tot.w * b2[3];
            out[0] = acc;
        }
    }
}

extern "C" void kernel_launch(void* const* d_in, const int* in_sizes, int n_in,
                              void* d_out, int out_size, void* d_ws, size_t ws_size,
                              hipStream_t stream) {
    const float* X   = (const float*)d_in[0];
    const int*   eid = (const int*)  d_in[1];
    const float* W1  = (const float*)d_in[2];
    const float* b1  = (const float*)d_in[3];
    const float* W2  = (const float*)d_in[4];
    const float* b2  = (const float*)d_in[5];
    float* out = (float*)d_out;

    char* ws = (char*)d_ws;
    unsigned short* W1t = (unsigned short*)ws;
    float* bpart     = (float*)(ws + WS_BPART);
    int*   bcnt      = (int*)  (ws + WS_BCNT);
    int*   sortedIdx = (int*)  (ws + WS_SIDX);

    hipLaunchKernelGGL(tnn_k1_fused,   dim3(32 + HIST_BLOCKS), dim3(256), 0, stream, eid, bcnt, W1, W1t);
    hipLaunchKernelGGL(tnn_k3_scatter, dim3(HIST_BLOCKS),      dim3(256), 0, stream, eid, bcnt, sortedIdx);
    hipLaunchKernelGGL(tnn_k4_mlp,     dim3(K4_BLOCKS),        dim3(512), 0, stream,
                       X, sortedIdx, bcnt, W1t, b1, W2, bpart);
    hipLaunchKernelGGL(tnn_k5_reduce,  dim3(1),                dim3(256), 0, stream, bpart, bcnt, b2, out);
}

// Round 11
// 37.884 us; speedup vs baseline: 2.4378x; 1.1247x over previous
//
#include <hip/hip_runtime.h>
#include <hip/hip_bf16.h>
#include <stdint.h>

#define N_ATOMS 131072
#define D_IN    128
#define D_HID   256
#define N_ELEM  4
#define NPAD    (N_ATOMS + N_ELEM * 64)   // 131328 slots max
#define K4_BLOCKS 512                      // 512 thr each; 2 blocks/CU
#define HIST_BLOCKS 128                    // 128 x 1024 atoms

typedef __attribute__((ext_vector_type(8))) short bf16x8;
typedef __attribute__((ext_vector_type(4))) float f32x4;
typedef unsigned long long ull;

// ws layout (bytes):
//   [0,       262144): W1t bf16 [4][256][128] (h-major, k contiguous)
//   [262272,  278656): bpart[4096] float (per-wave partials)
//   [278784,  280832): blockCounts[128][4] int
//   [287232,  812544): sortedIdx[NPAD] int
#define WS_BPART  262272
#define WS_BCNT   278784
#define WS_SIDX   287232

__device__ __forceinline__ unsigned short f2bf_rne(float f) {
    union { float f; unsigned u; } v; v.f = f;
    unsigned r = v.u + 0x7FFFu + ((v.u >> 16) & 1u);   // RNE
    return (unsigned short)(r >> 16);
}

__device__ __forceinline__ bf16x8 cvt8(f32x4 v0, f32x4 v1) {
    uint4 o;
    o.x = (__float_as_uint(v0[0]) >> 16) | (__float_as_uint(v0[1]) & 0xFFFF0000u);
    o.y = (__float_as_uint(v0[2]) >> 16) | (__float_as_uint(v0[3]) & 0xFFFF0000u);
    o.z = (__float_as_uint(v1[0]) >> 16) | (__float_as_uint(v1[1]) & 0xFFFF0000u);
    o.w = (__float_as_uint(v1[2]) >> 16) | (__float_as_uint(v1[3]) & 0xFFFF0000u);
    return __builtin_bit_cast(bf16x8, o);
}

// int4 butterfly reduce across a 64-lane wave (all lanes get the total)
__device__ __forceinline__ int4 wave_reduce4(int4 v) {
    #pragma unroll
    for (int off = 32; off; off >>= 1) {
        v.x += __shfl_xor(v.x, off);
        v.y += __shfl_xor(v.y, off);
        v.z += __shfl_xor(v.z, off);
        v.w += __shfl_xor(v.w, off);
    }
    return v;
}

// lanes-with-same-2bit-expert mask via two ballots
__device__ __forceinline__ ull same_expert_mask(int e) {
    ull m0 = __ballot(e & 1);
    ull m1 = __ballot(e & 2);
    ull m = (e & 1) ? m0 : ~m0;
    return m & ((e & 2) ? m1 : ~m1);
}

// K1 (fused): blocks 0..31 transpose W1 -> W1t bf16; blocks 32..159 histogram.
__global__ void tnn_k1_fused(const int* __restrict__ eid, int* __restrict__ bcnt,
                             const float* __restrict__ W1, unsigned short* __restrict__ W1t) {
    __shared__ float tile[64][65];
    __shared__ int lc[N_ELEM];
    int t = threadIdx.x;
    if (blockIdx.x < 32) {
        int b  = blockIdx.x;
        int e  = b >> 3;
        int k0 = ((b >> 2) & 1) * 64;
        int h0 = (b & 3) * 64;
        int cg = t & 15;
        int rr = t >> 4;
        const float* src = W1 + ((size_t)e * D_IN + k0) * D_HID + h0;
        #pragma unroll
        for (int j = 0; j < 4; ++j) {
            int row = rr + j * 16;
            f32x4 v = *(const f32x4*)(src + (size_t)row * D_HID + cg * 4);
            tile[row][cg * 4 + 0] = v[0];
            tile[row][cg * 4 + 1] = v[1];
            tile[row][cg * 4 + 2] = v[2];
            tile[row][cg * 4 + 3] = v[3];
        }
        __syncthreads();
        unsigned short* dst = W1t + ((size_t)e * D_HID + h0) * D_IN + k0;
        #pragma unroll
        for (int j = 0; j < 4; ++j) {
            int hrow = rr + j * 16;
            ushort4 o;
            o.x = f2bf_rne(tile[cg * 4 + 0][hrow]);
            o.y = f2bf_rne(tile[cg * 4 + 1][hrow]);
            o.z = f2bf_rne(tile[cg * 4 + 2][hrow]);
            o.w = f2bf_rne(tile[cg * 4 + 3][hrow]);
            *(ushort4*)(dst + (size_t)hrow * D_IN + cg * 4) = o;
        }
    } else {
        int hb = blockIdx.x - 32;
        int lane = t & 63;
        if (t < N_ELEM) lc[t] = 0;
        __syncthreads();
        int base = hb * 1024;
        #pragma unroll
        for (int r = 0; r < 4; ++r) {
            int e = eid[base + r * 256 + t];
            ull m = same_expert_mask(e);
            if (lane == __builtin_ctzll(m))
                atomicAdd(&lc[e], __popcll(m));       // 4 atomics/wave, not 64
        }
        __syncthreads();
        if (t < N_ELEM) bcnt[hb * 4 + t] = lc[t];
    }
}

// K3: scatter; per-block bases by wave-0 butterfly scan; ballot ranking.
__global__ void tnn_k3_scatter(const int* __restrict__ eid, const int* __restrict__ bcnt,
                               int* __restrict__ sortedIdx) {
    __shared__ int lc[N_ELEM];
    __shared__ int base4[N_ELEM];
    int t = threadIdx.x;
    int b = blockIdx.x;
    int lane = t & 63;
    if (t < N_ELEM) lc[t] = 0;
    if (t < 64) {
        int4 cl = ((const int4*)bcnt)[t];
        int4 ch = ((const int4*)bcnt)[t + 64];
        int4 tot = {cl.x + ch.x, cl.y + ch.y, cl.z + ch.z, cl.w + ch.w};
        tot = wave_reduce4(tot);
        int4 pre = {(t < b) ? cl.x : 0, (t < b) ? cl.y : 0,
                    (t < b) ? cl.z : 0, (t < b) ? cl.w : 0};
        if (t + 64 < b) { pre.x += ch.x; pre.y += ch.y; pre.z += ch.z; pre.w += ch.w; }
        pre = wave_reduce4(pre);
        if (t == 0) {
            int st0 = 0;
            int st1 = st0 + ((tot.x + 63) & ~63);
            int st2 = st1 + ((tot.y + 63) & ~63);
            int st3 = st2 + ((tot.z + 63) & ~63);
            base4[0] = st0 + pre.x;
            base4[1] = st1 + pre.y;
            base4[2] = st2 + pre.z;
            base4[3] = st3 + pre.w;
        }
    }
    __syncthreads();
    int base = b * 1024;
    ull below = (lane == 63) ? 0x7FFFFFFFFFFFFFFFULL : ((1ULL << lane) - 1);
    #pragma unroll
    for (int r = 0; r < 4; ++r) {
        int i = base + r * 256 + t;
        int e = eid[i];
        ull m = same_expert_mask(e);
        int f = __builtin_ctzll(m);
        int rank = __popcll(m & below);
        int wbase = 0;
        if (lane == f) wbase = atomicAdd(&lc[e], __popcll(m));
        wbase = __shfl(wbase, f);
        sortedIdx[base4[e] + wbase + rank] = i;
    }
}

// nt-loop body, FULL-templated: full tiles (all but <=4 per expert) skip masks.
template<bool FULL>
__device__ __forceinline__ float nt_loop(const unsigned char* ldsB, const float2* ldsBW,
                                         unsigned ldso, const bf16x8 a0[4], const bf16x8 a1[4],
                                         int tb, int rend, int lk, int l15, float fnval) {
    const float C2 = 2.8853900817779268f;
    float partial = 0.f;
    #pragma unroll 1
    for (int nt = 0; nt < 16; ++nt) {
        const unsigned char* lb = ldsB + ldso + (unsigned)nt * 256u;
        bf16x8 cur0 = *(const bf16x8*)(lb);
        bf16x8 cur1 = *(const bf16x8*)(lb + 16384);
        bf16x8 cur2 = *(const bf16x8*)(lb + 32768);
        bf16x8 cur3 = *(const bf16x8*)(lb + 49152);
        float2 bw = ldsBW[nt * 16 + l15];

        f32x4 acc0 = {0.f, 0.f, 0.f, 0.f};
        f32x4 acc1 = {0.f, 0.f, 0.f, 0.f};
        acc0 = __builtin_amdgcn_mfma_f32_16x16x32_bf16(a0[0], cur0, acc0, 0, 0, 0);
        acc1 = __builtin_amdgcn_mfma_f32_16x16x32_bf16(a1[0], cur0, acc1, 0, 0, 0);
        acc0 = __builtin_amdgcn_mfma_f32_16x16x32_bf16(a0[1], cur1, acc0, 0, 0, 0);
        acc1 = __builtin_amdgcn_mfma_f32_16x16x32_bf16(a1[1], cur1, acc1, 0, 0, 0);
        acc0 = __builtin_amdgcn_mfma_f32_16x16x32_bf16(a0[2], cur2, acc0, 0, 0, 0);
        acc1 = __builtin_amdgcn_mfma_f32_16x16x32_bf16(a1[2], cur2, acc1, 0, 0, 0);
        acc0 = __builtin_amdgcn_mfma_f32_16x16x32_bf16(a0[3], cur3, acc0, 0, 0, 0);
        acc1 = __builtin_amdgcn_mfma_f32_16x16x32_bf16(a1[3], cur3, acc1, 0, 0, 0);

        // tanh(p) = 1 - 2/(exp2(C2*p)+1); sum w2*tanh = w2*(nval - 2*sum(rcp))
        float rsum = 0.f;
        #pragma unroll
        for (int r = 0; r < 4; ++r) {
            float e0 = __builtin_amdgcn_exp2f(fmaf(C2, acc0[r], bw.x));
            float e1 = __builtin_amdgcn_exp2f(fmaf(C2, acc1[r], bw.x));
            float rc0 = __builtin_amdgcn_rcpf(e0 + 1.f);
            float rc1 = __builtin_amdgcn_rcpf(e1 + 1.f);
            if (!FULL) {
                rc0 = (tb + lk * 4 + r      < rend) ? rc0 : 0.f;
                rc1 = (tb + 16 + lk * 4 + r < rend) ? rc1 : 0.f;
            }
            rsum += rc0 + rc1;
        }
        partial = fmaf(bw.y, fmaf(-2.f, rsum, fnval), partial);
    }
    return partial;
}

// K4: 512 blocks x 512 thr (2 blocks/CU, 4 waves/SIMD). Block stages its
// expert's FULL W1t into LDS (64 KB, k-major, conflict-free) + {b1*C2,w2}
// table. Wave = 32-atom tile; A in regs (32 VGPR); rolled nt loop.
__global__ __launch_bounds__(512, 4) void tnn_k4_mlp(
        const float* __restrict__ X, const int* __restrict__ sortedIdx,
        const int* __restrict__ bcnt, const unsigned short* __restrict__ W1t,
        const float* __restrict__ b1, const float* __restrict__ W2,
        float* __restrict__ bpart) {
    __shared__ unsigned char ldsB[65536];   // [16 kblk][256 h][16 B]  (k-major)
    __shared__ float2 ldsBW[256];           // {b1*C2, w2} per h
    const float C2 = 2.8853900817779268f;

    int t = threadIdx.x;
    int wid  = t >> 6;                       // 0..7
    int lane = t & 63;
    int l15  = lane & 15;
    int lk   = lane >> 4;
    int e    = blockIdx.x & 3;
    int q    = blockIdx.x >> 2;              // 0..127

    // ---- per-wave redundant scan of bcnt -> counts + startArr for expert e ----
    int4 cl = ((const int4*)bcnt)[lane];
    int4 ch = ((const int4*)bcnt)[lane + 64];
    int4 tot = {cl.x + ch.x, cl.y + ch.y, cl.z + ch.z, cl.w + ch.w};
    tot = wave_reduce4(tot);
    int cnts[4] = {tot.x, tot.y, tot.z, tot.w};
    int st[5];
    st[0] = 0;
    #pragma unroll
    for (int i = 0; i < 4; ++i) st[i + 1] = st[i] + ((cnts[i] + 63) & ~63);
    int bstart = st[e];
    int cnt    = cnts[e];
    int rend   = bstart + cnt;
    int Te     = (st[e + 1] - bstart) >> 5;       // 32-atom tiles
    int fb     = (cnt > 0) ? sortedIdx[bstart] : 0;

    // ---- stage B (k-major): thread t = (h-row t>>1, k-half t&1) ----
    {
        int hrow  = t >> 1;
        int khalf = t & 1;
        const unsigned short* src = W1t + ((size_t)e * D_HID + hrow) * D_IN + khalf * 64;
        #pragma unroll
        for (int jj = 0; jj < 8; ++jj) {
            bf16x8 v = *(const bf16x8*)(src + jj * 8);
            *(bf16x8*)(ldsB + (khalf * 8 + jj) * 4096 + hrow * 16) = v;
        }
        if (t < 256) ldsBW[t] = make_float2(b1[e * D_HID + t] * C2, W2[e * D_HID + t]);
    }
    __syncthreads();

    unsigned ldso = (unsigned)lk * 4096u + (unsigned)l15 * 16u;

    float partial = 0.f;
    for (int tt = q * 8 + wid; tt < Te; tt += 1024) {
        int tb = bstart + tt * 32;
        bool full = (tb + 32 <= rend);

        int slot0 = tb + l15, slot1 = slot0 + 16;
        int r0 = (slot0 < rend) ? sortedIdx[slot0] : fb;
        int r1 = (slot1 < rend) ? sortedIdx[slot1] : fb;

        // ---- A: 32 atoms x 128 k -> regs ----
        bf16x8 a0[4], a1[4];
        const float* x0 = X + (size_t)r0 * D_IN + lk * 8;
        const float* x1 = X + (size_t)r1 * D_IN + lk * 8;
        #pragma unroll
        for (int ks = 0; ks < 4; ++ks)
            a0[ks] = cvt8(*(const f32x4*)(x0 + ks * 32), *(const f32x4*)(x0 + ks * 32 + 4));
        #pragma unroll
        for (int ks = 0; ks < 4; ++ks)
            a1[ks] = cvt8(*(const f32x4*)(x1 + ks * 32), *(const f32x4*)(x1 + ks * 32 + 4));

        if (full) {
            partial += nt_loop<true >(ldsB, ldsBW, ldso, a0, a1, tb, rend, lk, l15, 8.f);
        } else {
            int nv = 0;
            #pragma unroll
            for (int m = 0; m < 2; ++m)
                #pragma unroll
                for (int r = 0; r < 4; ++r)
                    nv += (tb + m * 16 + lk * 4 + r < rend) ? 1 : 0;
            partial += nt_loop<false>(ldsB, ldsBW, ldso, a0, a1, tb, rend, lk, l15, (float)nv);
        }
    }

    #pragma unroll
    for (int off = 32; off; off >>= 1)
        partial += __shfl_down(partial, off);
    if (lane == 0) bpart[blockIdx.x * 8 + wid] = partial;   // plain store
}

// K5: reduce 4096 per-wave partials + analytic bias (counts recomputed inline).
__global__ void tnn_k5_reduce(const float* __restrict__ bpart, const int* __restrict__ bcnt,
                              const float* __restrict__ b2, float* __restrict__ out) {
    __shared__ float r[4];
    int t = threadIdx.x;
    float s = 0.f;
    #pragma unroll
    for (int j = 0; j < 16; ++j) s += bpart[j * 256 + t];
    #pragma unroll
    for (int off = 32; off; off >>= 1)
        s += __shfl_down(s, off);
    if ((t & 63) == 0) r[t >> 6] = s;
    __syncthreads();
    if (t < 64) {
        int4 cl = ((const int4*)bcnt)[t];
        int4 ch = ((const int4*)bcnt)[t + 64];
        int4 tot = {cl.x + ch.x, cl.y + ch.y, cl.z + ch.z, cl.w + ch.w};
        tot = wave_reduce4(tot);
        if (t == 0) {
            float acc = r[0] + r[1] + r[2] + r[3];
            acc += (float)tot.x * b2[0];
            acc += (float)tot.y * b2[1];
            acc += (float)tot.z * b2[2];
            acc += (float)tot.w * b2[3];
            out[0] = acc;
        }
    }
}

extern "C" void kernel_launch(void* const* d_in, const int* in_sizes, int n_in,
                              void* d_out, int out_size, void* d_ws, size_t ws_size,
                              hipStream_t stream) {
    const float* X   = (const float*)d_in[0];
    const int*   eid = (const int*)  d_in[1];
    const float* W1  = (const float*)d_in[2];
    const float* b1  = (const float*)d_in[3];
    const float* W2  = (const float*)d_in[4];
    const float* b2  = (const float*)d_in[5];
    float* out = (float*)d_out;

    char* ws = (char*)d_ws;
    unsigned short* W1t = (unsigned short*)ws;
    float* bpart     = (float*)(ws + WS_BPART);
    int*   bcnt      = (int*)  (ws + WS_BCNT);
    int*   sortedIdx = (int*)  (ws + WS_SIDX);

    hipLaunchKernelGGL(tnn_k1_fused,   dim3(32 + HIST_BLOCKS), dim3(256), 0, stream, eid, bcnt, W1, W1t);
    hipLaunchKernelGGL(tnn_k3_scatter, dim3(HIST_BLOCKS),      dim3(256), 0, stream, eid, bcnt, sortedIdx);
    hipLaunchKernelGGL(tnn_k4_mlp,     dim3(K4_BLOCKS),        dim3(512), 0, stream,
                       X, sortedIdx, bcnt, W1t, b1, W2, bpart);
    hipLaunchKernelGGL(tnn_k5_reduce,  dim3(1),                dim3(256), 0, stream, bpart, bcnt, b2, out);
}